// Round 1
// baseline (184.887 us; speedup 1.0000x reference)
//
#include <hip/hip_runtime.h>
#include <math.h>

#define N_HIST 200000
#define TOPIC 128
#define HID 128
#define KSEL 50
#define EQ_CAP 4096
#define NEG_INF (-3.402823466e38f)
// log(float32(1.0 - 1e-7)) = log(0.99999988079071045)
#define LOG_DECAY (-1.1920930e-07f)

// ws layout (4-byte words):
enum { WS_HIST = 0,              // 65536 bins
       WS_CTRL = 65536,          // [0]=cntHi [1]=cntEq [2]=binB [3]=C1
       WS_ALPHA = 65552,         // N_HIST floats
       WS_HIVAL = WS_ALPHA + N_HIST,   // 64
       WS_HIIDX = WS_HIVAL + 64,       // 64
       WS_EQVAL = WS_HIIDX + 64,       // EQ_CAP
       WS_EQIDX = WS_EQVAL + EQ_CAP }; // EQ_CAP

__device__ __forceinline__ unsigned keyOf(float f) {
    unsigned u = __float_as_uint(f);
    return (u & 0x80000000u) ? ~u : (u | 0x80000000u);
}

// Kernel 1: alpha[i] = dot(vs[i], v); histogram of top-16 key bits.
// One wave per row; lane reads float2 -> 512B coalesced per row.
__global__ __launch_bounds__(256) void alpha_hist_kernel(
        const float* __restrict__ vs, const float* __restrict__ v,
        float* __restrict__ alpha, unsigned* __restrict__ hist) {
    const int lane = threadIdx.x & 63;
    const int wave = (blockIdx.x * blockDim.x + threadIdx.x) >> 6;
    const int nwaves = (gridDim.x * blockDim.x) >> 6;
    const float2 vv = ((const float2*)v)[lane];
    for (int row = wave; row < N_HIST; row += nwaves) {
        float2 a = ((const float2*)vs)[row * 64 + lane];
        float sum = a.x * vv.x + a.y * vv.y;
        #pragma unroll
        for (int off = 32; off; off >>= 1) sum += __shfl_xor(sum, off);
        if (lane == 0) {
            alpha[row] = sum;
            atomicAdd(&hist[keyOf(sum) >> 16], 1u);
        }
    }
}

// Kernel 2: find bin B holding the KSEL-th largest and count C1 strictly above.
__global__ __launch_bounds__(256) void scan_kernel(
        const unsigned* __restrict__ hist, unsigned* __restrict__ ctrl) {
    __shared__ unsigned p[256];
    const int t = threadIdx.x;
    unsigned s = 0;
    const uint4* h4 = (const uint4*)(hist + t * 256);
    #pragma unroll 8
    for (int i = 0; i < 64; ++i) { uint4 q = h4[i]; s += q.x + q.y + q.z + q.w; }
    p[t] = s;
    __syncthreads();
    if (t == 0) {
        unsigned cum = 0; int B = 0; unsigned C1 = 0;
        for (int c = 255; c >= 0; --c) {
            if (cum + p[c] >= KSEL) {
                for (int b = c * 256 + 255; b >= c * 256; --b) {
                    unsigned hb = hist[b];
                    if (cum + hb >= KSEL) { B = b; C1 = cum; break; }
                    cum += hb;
                }
                break;
            }
            cum += p[c];
        }
        ctrl[2] = (unsigned)B;
        ctrl[3] = C1;
    }
}

// Kernel 3: gather candidates from the 800KB alpha array (L2-resident).
__global__ __launch_bounds__(256) void collect_kernel(
        const float* __restrict__ alpha, unsigned* __restrict__ ctrl,
        float* __restrict__ hiVal, unsigned* __restrict__ hiIdx,
        float* __restrict__ eqVal, unsigned* __restrict__ eqIdx) {
    const unsigned B = ctrl[2];
    int i = blockIdx.x * blockDim.x + threadIdx.x;
    const int stride = gridDim.x * blockDim.x;
    for (; i < N_HIST; i += stride) {
        float a = alpha[i];
        unsigned k16 = keyOf(a) >> 16;
        if (k16 > B) {
            unsigned pos = atomicAdd(&ctrl[0], 1u);
            if (pos < 64u) { hiVal[pos] = a; hiIdx[pos] = (unsigned)i; }
        } else if (k16 == B) {
            unsigned pos = atomicAdd(&ctrl[1], 1u);
            if (pos < (unsigned)EQ_CAP) { eqVal[pos] = a; eqIdx[pos] = (unsigned)i; }
        }
    }
}

// Kernel 4: finish top-k, decay, softmax, attn gather, score head, GRU step.
__global__ __launch_bounds__(512) void final_kernel(
        const float* __restrict__ v, const float* __restrict__ s_in,
        const float* __restrict__ t_in, const float* __restrict__ hs,
        const float* __restrict__ ts,
        const float* __restrict__ W_ih, const float* __restrict__ b_ih,
        const float* __restrict__ W_hh, const float* __restrict__ b_hh,
        const float* __restrict__ W_score, const float* __restrict__ b_score,
        const unsigned* __restrict__ ctrl,
        const float* __restrict__ hiVal, const unsigned* __restrict__ hiIdx,
        const float* __restrict__ eqVal, const unsigned* __restrict__ eqIdx,
        float* __restrict__ out) {
    __shared__ float eqV[EQ_CAP];
    __shared__ unsigned eqI[EQ_CAP];
    __shared__ float selV[KSEL];
    __shared__ unsigned selI[KSEL];
    __shared__ float w[KSEL];
    __shared__ float red[512];
    __shared__ int redi[512];
    __shared__ float xv[TOPIC + 1];
    __shared__ float h0[HID];
    __shared__ float attn[HID];
    __shared__ float gi[3 * HID];
    __shared__ float gh[3 * HID];
    __shared__ int sS;

    const int t = threadIdx.x;
    const unsigned C1 = min(ctrl[3], (unsigned)KSEL);
    const unsigned ec = min(ctrl[1], (unsigned)EQ_CAP);
    int need = KSEL - (int)C1;
    if (need < 0) need = 0;
    if ((unsigned)need > ec) need = (int)ec;

    if (t < (int)C1) { selV[t] = hiVal[t]; selI[t] = hiIdx[t]; }
    for (int i = t; i < (int)ec; i += 512) { eqV[i] = eqVal[i]; eqI[i] = eqIdx[i]; }
    // stage x = [v, s] and h0 = hs[-1]
    if (t < TOPIC) xv[t] = v[t];
    if (t == 511) xv[TOPIC] = s_in[0];
    if (t >= 128 && t < 256) h0[t - 128] = hs[(size_t)(N_HIST - 1) * HID + (t - 128)];
    __syncthreads();

    // iteratively pick the `need` largest from the eq pool
    for (int j = 0; j < need; ++j) {
        float best = NEG_INF; int bi = -1;
        for (int i = t; i < (int)ec; i += 512)
            if (eqV[i] > best) { best = eqV[i]; bi = i; }
        red[t] = best; redi[t] = bi;
        __syncthreads();
        for (int off = 256; off; off >>= 1) {
            if (t < off && red[t + off] > red[t]) { red[t] = red[t + off]; redi[t] = redi[t + off]; }
            __syncthreads();
        }
        if (t == 0) {
            int p = redi[0];
            selV[C1 + j] = eqV[p]; selI[C1 + j] = eqI[p];
            eqV[p] = NEG_INF;
        }
        __syncthreads();
    }

    // decay + softmax (K<=50, trivial serial)
    if (t == 0) {
        int S = (int)C1 + need;
        sS = S;
        float tt = t_in[0];
        float m = NEG_INF;
        for (int k = 0; k < S; ++k) {
            float d = tt - ts[selI[k]];
            selV[k] = selV[k] * expf(d * LOG_DECAY);
            m = fmaxf(m, selV[k]);
        }
        float sum = 0.f;
        for (int k = 0; k < S; ++k) { w[k] = expf(selV[k] - m); sum += w[k]; }
        float inv = 1.f / sum;
        for (int k = 0; k < S; ++k) w[k] *= inv;
    }
    __syncthreads();

    // attn_h[h] = sum_k w[k] * hs[idx[k]][h]
    if (t < HID) {
        float acc = 0.f;
        const int S = sS;
        for (int k = 0; k < S; ++k) acc += w[k] * hs[(size_t)selI[k] * HID + t];
        attn[t] = acc;
    }
    __syncthreads();

    // score = [v, attn] . W_score + b_score
    float sc = 0.f;
    if (t < 128) sc = xv[t] * W_score[t] + attn[t] * W_score[128 + t];
    red[t] = sc;
    __syncthreads();
    for (int off = 256; off; off >>= 1) {
        if (t < off) red[t] += red[t + off];
        __syncthreads();
    }
    if (t == 0) out[0] = red[0] + b_score[0];

    // GRU step
    if (t < 3 * HID) {
        const float* wr = W_ih + t * (TOPIC + 1);
        float acc = b_ih[t];
        #pragma unroll 4
        for (int j = 0; j < TOPIC + 1; ++j) acc += wr[j] * xv[j];
        gi[t] = acc;
        const float* wh = W_hh + t * HID;
        float acc2 = b_hh[t];
        #pragma unroll 4
        for (int j = 0; j < HID; ++j) acc2 += wh[j] * h0[j];
        gh[t] = acc2;
    }
    __syncthreads();
    if (t < HID) {
        float r = 1.f / (1.f + expf(-(gi[t] + gh[t])));
        float z = 1.f / (1.f + expf(-(gi[HID + t] + gh[HID + t])));
        float n = tanhf(gi[2 * HID + t] + r * gh[2 * HID + t]);
        out[1 + t] = (1.f - z) * n + z * h0[t];
    }
}

extern "C" void kernel_launch(void* const* d_in, const int* in_sizes, int n_in,
                              void* d_out, int out_size, void* d_ws, size_t ws_size,
                              hipStream_t stream) {
    const float* v       = (const float*)d_in[0];
    const float* s_in    = (const float*)d_in[1];
    const float* t_in    = (const float*)d_in[2];
    const float* vs      = (const float*)d_in[3];
    const float* hs      = (const float*)d_in[4];
    const float* ts      = (const float*)d_in[5];
    const float* W_ih    = (const float*)d_in[6];
    const float* b_ih    = (const float*)d_in[7];
    const float* W_hh    = (const float*)d_in[8];
    const float* b_hh    = (const float*)d_in[9];
    const float* W_score = (const float*)d_in[10];
    const float* b_score = (const float*)d_in[11];
    float* out = (float*)d_out;

    unsigned* ws  = (unsigned*)d_ws;
    unsigned* hist = ws + WS_HIST;
    unsigned* ctrl = ws + WS_CTRL;
    float*    alpha = (float*)(ws + WS_ALPHA);
    float*    hiVal = (float*)(ws + WS_HIVAL);
    unsigned* hiIdx = ws + WS_HIIDX;
    float*    eqVal = (float*)(ws + WS_EQVAL);
    unsigned* eqIdx = ws + WS_EQIDX;

    // zero hist + ctrl (contiguous region)
    hipMemsetAsync(d_ws, 0, (size_t)(WS_ALPHA) * 4, stream);

    alpha_hist_kernel<<<2048, 256, 0, stream>>>(vs, v, alpha, hist);
    scan_kernel<<<1, 256, 0, stream>>>(hist, ctrl);
    collect_kernel<<<256, 256, 0, stream>>>(alpha, ctrl, hiVal, hiIdx, eqVal, eqIdx);
    final_kernel<<<1, 512, 0, stream>>>(v, s_in, t_in, hs, ts,
                                        W_ih, b_ih, W_hh, b_hh, W_score, b_score,
                                        ctrl, hiVal, hiIdx, eqVal, eqIdx, out);
}